// Round 1
// baseline (212.453 us; speedup 1.0000x reference)
//
#include <hip/hip_runtime.h>

typedef __attribute__((ext_vector_type(8))) _Float16 f16x8;
typedef __attribute__((ext_vector_type(4))) float f32x4;

typedef __attribute__((address_space(3))) unsigned int lds_u32;
typedef const __attribute__((address_space(1))) unsigned int g_u32;

#define DEV_INLINE __device__ __forceinline__

constexpr int B_ = 128, N_ = 32, D_ = 256, H_ = 1024;
constexpr int JG = 4;        // j's per block
constexpr int HC = 128;      // h-chunk width
constexpr int NCH = H_ / HC; // 8 chunks
constexpr int XPAD = 260;    // fp32 X row stride in LDS (bank-spread, 16B-aligned)

// LDS map (bytes):
//  [0,      65536)  wbuf0  (start of block: doubles as X staging [32][260] f32 = 33280 B)
//  [65536, 131072)  wbuf1
//  [131072,147584)  s [4][1032] f32
//  [147584,151680)  b1 [1024] f32
constexpr int LDS_BYTES = 151680;

DEV_INLINE void gload_lds16(const void* g, void* l) {
    __builtin_amdgcn_global_load_lds((g_u32*)g, (lds_u32*)l, 16, 0, 0);
}

#define BARRIER() asm volatile("s_barrier" ::: "memory")

// ---------------------------------------------------------------------------
// prep: W1T[h*256+k] = f16(W1[k*1024+h]);  W2T[d*1024+h] = f16(W2[h*256+d])
// ---------------------------------------------------------------------------
__global__ void prep_kernel(const float* __restrict__ W1, const float* __restrict__ W2,
                            _Float16* __restrict__ W1T, _Float16* __restrict__ W2T) {
    int t = blockIdx.x * blockDim.x + threadIdx.x; // 0..524287
    if (t < 262144) {
        int h = t >> 8, k = t & 255;
        W1T[t] = (_Float16)W1[k * 1024 + h];
    } else {
        int u = t - 262144;
        int d = u >> 10, h = u & 1023;
        W2T[u] = (_Float16)W2[h * 256 + d];
    }
}

// ---------------------------------------------------------------------------
// main: grid = B * (N/JG) = 1024 blocks, 512 threads (8 waves)
// wave w: jl = w>>1 (j-slot 0..3), colbase = (w&1)*64 (within 128-col chunk)
// ---------------------------------------------------------------------------
__global__ __launch_bounds__(512, 2)
void interaction_main(const float* __restrict__ Xg, const float* __restrict__ b1g,
                      const float* __restrict__ b2g, const _Float16* __restrict__ W1T,
                      const _Float16* __restrict__ W2T, float* __restrict__ outg) {
    __shared__ __align__(16) unsigned char smem[LDS_BYTES];

    const int tid = threadIdx.x;
    const int w = tid >> 6, l = tid & 63, l15 = l & 15, lg = l >> 4;
    const int bid = blockIdx.x;
    const int b = bid >> 3, jg = bid & 7;
    const int j0 = jg * JG;
    const int jl = w >> 1;
    const int colbase = (w & 1) * 64;

    float* Xs  = (float*)smem;
    float* s_f = (float*)(smem + 131072);
    float* b1s = (float*)(smem + 147584);

    // ---- prologue: X_b -> LDS (padded), b1 -> LDS, zero s ----
    {
        const float* xb = Xg + (size_t)b * (N_ * D_);
        int row = tid >> 4, c0 = (tid & 15) * 16;
        #pragma unroll
        for (int q = 0; q < 4; ++q) {
            f32x4 v = *(const f32x4*)(xb + row * 256 + c0 + q * 4);
            *(f32x4*)(Xs + row * XPAD + c0 + q * 4) = v;
        }
        b1s[tid]       = b1g[tid];
        b1s[tid + 512] = b1g[tid + 512];
        for (int i = tid; i < 4 * 1032; i += 512) s_f[i] = 0.f;
    }
    __syncthreads();

    // ---- build A fragments: P[row][k] = X[i][k] * X[j0+jl][k], fp16 ----
    // wave rows: i = rt*16 + l15 (rt=0,1); per-lane k = ks*32 + lg*8 + [0..7]
    f16x8 afrag[2][8];
    {
        const float* xj = Xs + (j0 + jl) * XPAD;
        #pragma unroll
        for (int ks = 0; ks < 8; ++ks) {
            int k0 = ks * 32 + lg * 8;
            f32x4 xjA = *(const f32x4*)(xj + k0);
            f32x4 xjB = *(const f32x4*)(xj + k0 + 4);
            #pragma unroll
            for (int rt = 0; rt < 2; ++rt) {
                const float* xi = Xs + (rt * 16 + l15) * XPAD + k0;
                f32x4 a0 = *(const f32x4*)(xi);
                f32x4 a1 = *(const f32x4*)(xi + 4);
                f16x8 a;
                a[0] = (_Float16)(a0[0] * xjA[0]);
                a[1] = (_Float16)(a0[1] * xjA[1]);
                a[2] = (_Float16)(a0[2] * xjA[2]);
                a[3] = (_Float16)(a0[3] * xjA[3]);
                a[4] = (_Float16)(a1[0] * xjB[0]);
                a[5] = (_Float16)(a1[1] * xjB[1]);
                a[6] = (_Float16)(a1[2] * xjB[2]);
                a[7] = (_Float16)(a1[3] * xjB[3]);
                afrag[rt][ks] = a;
            }
        }
    }
    __syncthreads(); // X region free -> becomes wbuf0

    // ---- stage W1 chunk c into buf (c&1): 64KB, linear LDS dest,
    //      inverse-XOR-swizzled global source (read side applies XOR) ----
    auto stage = [&](int c) {
        const int bufbase = (c & 1) * 65536;
        #pragma unroll
        for (int p = 0; p < 8; ++p) {
            int hc   = (w << 4) + (p << 1) + (l >> 5);     // row within chunk
            int srco = ((l & 31) ^ (hc & 7)) << 3;         // permuted k-oct
            const _Float16* src = W1T + (size_t)(c * HC + hc) * 256 + srco;
            void* dst = smem + bufbase + w * 8192 + p * 1024; // wave-uniform
            gload_lds16(src, dst);
        }
    };

    stage(0);

    for (int c = 0; c < NCH; ++c) {
        if (c + 1 < NCH) {
            stage(c + 1);
            asm volatile("s_waitcnt vmcnt(8)" ::: "memory"); // stage(c) landed
        } else {
            asm volatile("s_waitcnt vmcnt(0)" ::: "memory");
        }
        BARRIER();

        const int bufbase = (c & 1) * 65536;
        f32x4 acc0[4] = {};
        f32x4 acc1[4] = {};
        #pragma unroll
        for (int ks = 0; ks < 8; ++ks) {
            #pragma unroll
            for (int ct = 0; ct < 4; ++ct) {
                int hc = colbase + ct * 16 + l15;
                int boff = bufbase + hc * 512 + ((ks * 64 + lg * 16) ^ ((hc & 7) << 4));
                f16x8 bfr = *(const f16x8*)(smem + boff);
                acc0[ct] = __builtin_amdgcn_mfma_f32_16x16x32_f16(afrag[0][ks], bfr, acc0[ct], 0, 0, 0);
                acc1[ct] = __builtin_amdgcn_mfma_f32_16x16x32_f16(afrag[1][ks], bfr, acc1[ct], 0, 0, 0);
            }
        }
        // epilogue: +b1, ReLU, reduce over 32 i-rows, accumulate into s
        #pragma unroll
        for (int ct = 0; ct < 4; ++ct) {
            int hcol = c * HC + colbase + ct * 16 + l15;
            float bv = b1s[hcol];
            float v = 0.f;
            #pragma unroll
            for (int r = 0; r < 4; ++r) {
                v += fmaxf(acc0[ct][r] + bv, 0.f);
                v += fmaxf(acc1[ct][r] + bv, 0.f);
            }
            v += __shfl_xor(v, 16, 64);
            v += __shfl_xor(v, 32, 64);
            if (l < 16) s_f[jl * 1032 + hcol] += v; // wave-exclusive slice, no race
        }
        BARRIER(); // all reads of buf(c&1) done before it is restaged at c+2
    }

    __syncthreads(); // s complete & visible

    // ---- layer 2: out[jl][d] = sum_h s[jl][h] * W2[h][d] + 32*b2[d]
    //      one M=16 MFMA pass; rows 0..3 real, 4..15 zero. B read from L2. ----
    #pragma unroll
    for (int t2 = 0; t2 < 2; ++t2) {
        int ct2 = w * 2 + t2; // 16 col-tiles over 8 waves
        f32x4 acc = {};
        #pragma unroll
        for (int ks = 0; ks < 32; ++ks) {
            f16x8 a;
            #pragma unroll
            for (int q = 0; q < 8; ++q) a[q] = (_Float16)0.f;
            if (l15 < 4) {
                const float* sp = s_f + l15 * 1032 + ks * 32 + lg * 8;
                f32x4 s0 = *(const f32x4*)(sp);
                f32x4 s1 = *(const f32x4*)(sp + 4);
                a[0] = (_Float16)s0[0]; a[1] = (_Float16)s0[1];
                a[2] = (_Float16)s0[2]; a[3] = (_Float16)s0[3];
                a[4] = (_Float16)s1[0]; a[5] = (_Float16)s1[1];
                a[6] = (_Float16)s1[2]; a[7] = (_Float16)s1[3];
            }
            f16x8 bfr = *(const f16x8*)(W2T + (size_t)(ct2 * 16 + l15) * 1024 + ks * 32 + lg * 8);
            acc = __builtin_amdgcn_mfma_f32_16x16x32_f16(a, bfr, acc, 0, 0, 0);
        }
        if (l < 16) {
            int d = ct2 * 16 + l;
            float bb2 = 32.f * b2g[d];
            #pragma unroll
            for (int r = 0; r < 4; ++r) { // row r == jl r
                outg[(size_t)(b * N_ + j0 + r) * D_ + d] = acc[r] + bb2;
            }
        }
    }
}

// ---------------------------------------------------------------------------
extern "C" void kernel_launch(void* const* d_in, const int* in_sizes, int n_in,
                              void* d_out, int out_size, void* d_ws, size_t ws_size,
                              hipStream_t stream) {
    const float* X  = (const float*)d_in[0]; // [128,32,256]
    const float* W1 = (const float*)d_in[1]; // [256,1024]
    const float* b1 = (const float*)d_in[2]; // [1024]
    const float* W2 = (const float*)d_in[3]; // [1024,256]
    const float* b2 = (const float*)d_in[4]; // [256]
    float* out = (float*)d_out;              // [128,32,256]

    _Float16* W1T = (_Float16*)d_ws;         // [1024][256]
    _Float16* W2T = W1T + 262144;            // [256][1024]

    prep_kernel<<<dim3(2048), dim3(256), 0, stream>>>(W1, W2, W1T, W2T);
    interaction_main<<<dim3(B_ * (N_ / JG)), dim3(512), 0, stream>>>(X, b1, b2, W1T, W2T, out);
}

// Round 3
// 157.538 us; speedup vs baseline: 1.3486x; 1.3486x over previous
//
#include <hip/hip_runtime.h>

typedef __attribute__((ext_vector_type(8))) _Float16 f16x8;
typedef __attribute__((ext_vector_type(4))) _Float16 f16x4;
typedef __attribute__((ext_vector_type(4))) float f32x4;

typedef __attribute__((address_space(3))) unsigned int lds_u32;
typedef const __attribute__((address_space(1))) unsigned int g_u32;

#define DEV_INLINE __device__ __forceinline__

constexpr int B_ = 128, N_ = 32, D_ = 256, H_ = 1024;
constexpr int XPAD = 260;  // fp32 X row stride in LDS

// Main-kernel LDS map (bytes):
//  [0,     32768)  wbuf0   (prologue overlay: X staging [32][260] f32 = 33280 B spans into wbuf1)
//  [32768, 65536)  wbuf1
//  [65536, 69632)  b1s [1024] f32
constexpr int LDS_MAIN = 69632;

DEV_INLINE void gload_lds16(const void* g, void* l) {
    __builtin_amdgcn_global_load_lds((g_u32*)g, (lds_u32*)l, 16, 0, 0);
}

#define BARRIER() asm volatile("s_barrier" ::: "memory")

// ---------------------------------------------------------------------------
// prep2: coalesced 32x32 LDS-tile transposes + f32->f16 cast.
//  W1T[h][k] = f16(W1[k][h])   (W1 [256][1024] -> W1T [1024][256])
//  W2T[d][h] = f16(W2[h][d])   (W2 [1024][256] -> W2T [256][1024])
// ---------------------------------------------------------------------------
__global__ void prep2(const float* __restrict__ W1, const float* __restrict__ W2,
                      _Float16* __restrict__ W1T, _Float16* __restrict__ W2T) {
    __shared__ float tile[32][36];
    const int t = threadIdx.x;
    const int r = t >> 3, cq = (t & 7) * 4;
    int bb = blockIdx.x;
    if (bb < 256) {
        int tk = bb >> 5, th = bb & 31; // k-tile, h-tile
        *(f32x4*)&tile[r][cq] = *(const f32x4*)(W1 + (size_t)(tk * 32 + r) * 1024 + th * 32 + cq);
        __syncthreads();
        f16x4 o;
        #pragma unroll
        for (int q = 0; q < 4; ++q) o[q] = (_Float16)tile[cq + q][r];
        *(f16x4*)(W1T + (size_t)(th * 32 + r) * 256 + tk * 32 + cq) = o;
    } else {
        bb -= 256;
        int th = bb >> 3, td = bb & 7;  // h-tile, d-tile
        *(f32x4*)&tile[r][cq] = *(const f32x4*)(W2 + (size_t)(th * 32 + r) * 256 + td * 32 + cq);
        __syncthreads();
        f16x4 o;
        #pragma unroll
        for (int q = 0; q < 4; ++q) o[q] = (_Float16)tile[cq + q][r];
        *(f16x4*)(W2T + (size_t)(td * 32 + r) * 1024 + th * 32 + cq) = o;
    }
}

// ---------------------------------------------------------------------------
// main: grid = B * (N/8) = 512 blocks, 512 threads (8 waves), 2 blocks/CU.
// wave w handles j = j0 + w (all 32 i-rows, all 1024 h-cols), writes
// sg[(b*32+j)][h] = f16( sum_i relu( (x_i*x_j)@W1[:,h] + b1[h] ) ).
// W1T streamed in 16 chunks of 64 h-rows (32 KB), double-buffered, XOR-swizzled.
// ---------------------------------------------------------------------------
__global__ __launch_bounds__(512, 4)
void interaction_main(const float* __restrict__ Xg, const float* __restrict__ b1g,
                      const _Float16* __restrict__ W1T, _Float16* __restrict__ sg) {
    __shared__ __align__(16) unsigned char smem[LDS_MAIN];

    const int tid = threadIdx.x;
    const int w = tid >> 6, l = tid & 63, l15 = l & 15, lg = l >> 4;
    const int bid = blockIdx.x;
    const int b = bid >> 2, jg = bid & 3;
    const int j0 = jg * 8;

    float* Xs  = (float*)smem;
    float* b1s = (float*)(smem + 65536);

    // ---- prologue: X_b -> LDS (padded), b1 -> LDS ----
    {
        const float* xb = Xg + (size_t)b * (N_ * D_);
        int row = tid >> 4, c0 = (tid & 15) * 16;
        #pragma unroll
        for (int q = 0; q < 4; ++q)
            *(f32x4*)(Xs + row * XPAD + c0 + q * 4) = *(const f32x4*)(xb + row * 256 + c0 + q * 4);
        b1s[tid]       = b1g[tid];
        b1s[tid + 512] = b1g[tid + 512];
    }
    __syncthreads();

    // ---- build A fragments: P[row][k] = X[i][k] * X[j0+w][k], fp16 ----
    // wave rows: i = rt*16 + l15 (rt=0,1); per-lane k = ks*32 + lg*8 + [0..7]
    f16x8 afrag[2][8];
    {
        const float* xj = Xs + (j0 + w) * XPAD;
        #pragma unroll
        for (int ks = 0; ks < 8; ++ks) {
            int k0 = ks * 32 + lg * 8;
            f32x4 xjA = *(const f32x4*)(xj + k0);
            f32x4 xjB = *(const f32x4*)(xj + k0 + 4);
            #pragma unroll
            for (int rt = 0; rt < 2; ++rt) {
                const float* xi = Xs + (rt * 16 + l15) * XPAD + k0;
                f32x4 a0 = *(const f32x4*)(xi);
                f32x4 a1 = *(const f32x4*)(xi + 4);
                f16x8 a;
                a[0] = (_Float16)(a0[0] * xjA[0]);
                a[1] = (_Float16)(a0[1] * xjA[1]);
                a[2] = (_Float16)(a0[2] * xjA[2]);
                a[3] = (_Float16)(a0[3] * xjA[3]);
                a[4] = (_Float16)(a1[0] * xjB[0]);
                a[5] = (_Float16)(a1[1] * xjB[1]);
                a[6] = (_Float16)(a1[2] * xjB[2]);
                a[7] = (_Float16)(a1[3] * xjB[3]);
                afrag[rt][ks] = a;
            }
        }
    }
    __syncthreads(); // X region free -> becomes wbuf0/wbuf1

    // ---- stage W1 chunk c (64 rows x 512 B = 32 KB) into buf (c&1):
    //      linear LDS dest, inverse-XOR-swizzled global source ----
    auto stage = [&](int c) {
        const int bufbase = (c & 1) * 32768;
        #pragma unroll
        for (int p = 0; p < 4; ++p) {
            int hc   = ((p * 8 + w) << 1) + (l >> 5);     // row 0..63 within chunk
            int srco = ((l & 31) ^ (hc & 7)) << 3;        // permuted k-oct
            const _Float16* src = W1T + (size_t)(c * 64 + hc) * 256 + srco;
            void* dst = smem + bufbase + (p * 8 + w) * 1024; // wave-uniform
            gload_lds16(src, dst);
        }
    };

    stage(0);
    const size_t srow = (size_t)(b * 32 + j0 + w) * 1024;

    for (int c = 0; c < 16; ++c) {
        if (c < 15) {
            stage(c + 1);
            asm volatile("s_waitcnt vmcnt(4)" ::: "memory"); // stage(c) landed
        } else {
            asm volatile("s_waitcnt vmcnt(0)" ::: "memory");
        }
        BARRIER();

        const int bufbase = (c & 1) * 32768;
        f32x4 acc0[4] = {};
        f32x4 acc1[4] = {};
        __builtin_amdgcn_s_setprio(1);
        #pragma unroll
        for (int ks = 0; ks < 8; ++ks) {
            #pragma unroll
            for (int ct = 0; ct < 4; ++ct) {
                int hc = ct * 16 + l15;
                int boff = bufbase + hc * 512 + ((ks * 64 + lg * 16) ^ ((hc & 7) << 4));
                f16x8 bfr = *(const f16x8*)(smem + boff);
                acc0[ct] = __builtin_amdgcn_mfma_f32_16x16x32_f16(afrag[0][ks], bfr, acc0[ct], 0, 0, 0);
                acc1[ct] = __builtin_amdgcn_mfma_f32_16x16x32_f16(afrag[1][ks], bfr, acc1[ct], 0, 0, 0);
            }
        }
        __builtin_amdgcn_s_setprio(0);

        // epilogue: +b1, ReLU, reduce over 32 i-rows, store f16 to global s
        #pragma unroll
        for (int ct = 0; ct < 4; ++ct) {
            int hcol = c * 64 + ct * 16 + l15;
            float bv = b1s[hcol];
            float v = 0.f;
            #pragma unroll
            for (int r = 0; r < 4; ++r)
                v += fmaxf(acc0[ct][r] + bv, 0.f) + fmaxf(acc1[ct][r] + bv, 0.f);
            v += __shfl_xor(v, 16, 64);
            v += __shfl_xor(v, 32, 64);
            if (l < 16) sg[srow + hcol] = (_Float16)v;
        }
        BARRIER(); // buf(c&1) fully read before restage at c+2
    }
}

// ---------------------------------------------------------------------------
// layer2: out[m][d] = sum_h sg[m][h] * W2[h][d] + 32*b2[d], m = b*32+j.
// 256 blocks x 256 threads; block = 16-row stripe, wave w = 64-col slice.
// ---------------------------------------------------------------------------
__global__ __launch_bounds__(256, 4)
void layer2_kernel(const _Float16* __restrict__ sg, const _Float16* __restrict__ W2T,
                   const float* __restrict__ b2g, float* __restrict__ outg) {
    const int tid = threadIdx.x;
    const int w = tid >> 6, l = tid & 63, l15 = l & 15, lg = l >> 4;
    const int m0 = blockIdx.x * 16;

    f32x4 acc[4] = {};
    const _Float16* arow = sg  + (size_t)(m0 + l15) * 1024 + lg * 8;
    const _Float16* brow = W2T + (size_t)(w * 64 + l15) * 1024 + lg * 8;
    #pragma unroll
    for (int ks = 0; ks < 32; ++ks) {
        f16x8 af = *(const f16x8*)(arow + ks * 32);
        #pragma unroll
        for (int ct = 0; ct < 4; ++ct) {
            f16x8 bf = *(const f16x8*)(brow + (size_t)ct * 16 * 1024 + ks * 32);
            acc[ct] = __builtin_amdgcn_mfma_f32_16x16x32_f16(af, bf, acc[ct], 0, 0, 0);
        }
    }
    #pragma unroll
    for (int ct = 0; ct < 4; ++ct) {
        int d = w * 64 + ct * 16 + l15;
        float bb = 32.f * b2g[d];
        #pragma unroll
        for (int r = 0; r < 4; ++r)
            outg[(size_t)(m0 + lg * 4 + r) * 256 + d] = acc[ct][r] + bb;
    }
}

// ---------------------------------------------------------------------------
extern "C" void kernel_launch(void* const* d_in, const int* in_sizes, int n_in,
                              void* d_out, int out_size, void* d_ws, size_t ws_size,
                              hipStream_t stream) {
    const float* X  = (const float*)d_in[0]; // [128,32,256]
    const float* W1 = (const float*)d_in[1]; // [256,1024]
    const float* b1 = (const float*)d_in[2]; // [1024]
    const float* W2 = (const float*)d_in[3]; // [1024,256]
    const float* b2 = (const float*)d_in[4]; // [256]
    float* out = (float*)d_out;              // [128,32,256]

    _Float16* W1T = (_Float16*)d_ws;         // [1024][256]  512 KB
    _Float16* W2T = W1T + 262144;            // [256][1024]  512 KB
    _Float16* sgl = W2T + 262144;            // [4096][1024] 8 MB

    prep2<<<dim3(512), dim3(256), 0, stream>>>(W1, W2, W1T, W2T);
    interaction_main<<<dim3(512), dim3(512), 0, stream>>>(X, b1, W1T, sgl);
    layer2_kernel<<<dim3(256), dim3(256), 0, stream>>>(sgl, W2T, b2, out);
}

// Round 5
// 136.317 us; speedup vs baseline: 1.5585x; 1.1557x over previous
//
#include <hip/hip_runtime.h>

typedef __attribute__((ext_vector_type(8))) _Float16 f16x8;
typedef __attribute__((ext_vector_type(4))) _Float16 f16x4;
typedef __attribute__((ext_vector_type(4))) float f32x4;

typedef __attribute__((address_space(3))) unsigned int lds_u32;
typedef const __attribute__((address_space(1))) unsigned int g_u32;

#define DEV_INLINE __device__ __forceinline__

constexpr int B_ = 128, N_ = 32, D_ = 256, H_ = 1024;
constexpr int XPAD = 260;   // fp32 X row stride in LDS
constexpr int SROW = 1032;  // f16 row stride of s16 tile (2064 B, 16B-multiple)

// Main-kernel LDS map (bytes):
//  [0,     32768)  wbuf0   (prologue overlay: X staging [32][260] f32 = 33280 B spans into wbuf1)
//  [32768, 65536)  wbuf1
//  [65536, 98560)  s16 [16][1032] f16  (layer-1 output rows, j-local)
//  [98560,102656)  b1s [1024] f32
constexpr int LDS_MAIN = 102656;

DEV_INLINE void gload_lds16(const void* g, void* l) {
    __builtin_amdgcn_global_load_lds((g_u32*)g, (lds_u32*)l, 16, 0, 0);
}

#define BARRIER() asm volatile("s_barrier" ::: "memory")

// ---------------------------------------------------------------------------
// prep2: coalesced 32x32 LDS-tile transposes + f32->f16 cast.
//  W1T[h][k] = f16(W1[k][h])   (W1 [256][1024] -> W1T [1024][256])
//  W2T[d][h] = f16(W2[h][d])   (W2 [1024][256] -> W2T [256][1024])
// ---------------------------------------------------------------------------
__global__ void prep2(const float* __restrict__ W1, const float* __restrict__ W2,
                      _Float16* __restrict__ W1T, _Float16* __restrict__ W2T) {
    __shared__ float tile[32][36];
    const int t = threadIdx.x;
    const int r = t >> 3, cq = (t & 7) * 4;
    int bb = blockIdx.x;
    if (bb < 256) {
        int tk = bb >> 5, th = bb & 31; // k-tile, h-tile
        *(f32x4*)&tile[r][cq] = *(const f32x4*)(W1 + (size_t)(tk * 32 + r) * 1024 + th * 32 + cq);
        __syncthreads();
        f16x4 o;
        #pragma unroll
        for (int q = 0; q < 4; ++q) o[q] = (_Float16)tile[cq + q][r];
        *(f16x4*)(W1T + (size_t)(th * 32 + r) * 256 + tk * 32 + cq) = o;
    } else {
        bb -= 256;
        int th = bb >> 3, td = bb & 7;  // h-tile, d-tile
        *(f32x4*)&tile[r][cq] = *(const f32x4*)(W2 + (size_t)(th * 32 + r) * 256 + td * 32 + cq);
        __syncthreads();
        f16x4 o;
        #pragma unroll
        for (int q = 0; q < 4; ++q) o[q] = (_Float16)tile[cq + q][r];
        *(f16x4*)(W2T + (size_t)(td * 32 + r) * 1024 + th * 32 + cq) = o;
    }
}

// ---------------------------------------------------------------------------
// main (fused): grid = B * (N/16) = 256 blocks, 512 threads (8 waves), 1 block/CU.
// Block owns 16 consecutive j's. Wave w handles j = j0+w and j0+8+w (2 j's),
// so each W1 B-fragment LDS read feeds 4 MFMAs (2 rt x 2 j).
// Layer-1 row-sums -> s16 LDS tile [16 j][1024 h] f16; fused layer-2 tail:
// out[j][d] = s16[j][:] @ W2T[d][:] + 32*b2[d]   (M=16 MFMA pass, B from L2).
// ---------------------------------------------------------------------------
__global__ __launch_bounds__(512, 2)
void interaction_main(const float* __restrict__ Xg, const float* __restrict__ b1g,
                      const float* __restrict__ b2g, const _Float16* __restrict__ W1T,
                      const _Float16* __restrict__ W2T, float* __restrict__ outg) {
    __shared__ __align__(16) unsigned char smem[LDS_MAIN];

    const int tid = threadIdx.x;
    const int w = tid >> 6, l = tid & 63, l15 = l & 15, lg = l >> 4;
    const int bid = blockIdx.x;
    const int b = bid >> 1, jg = bid & 1;
    const int j0 = jg * 16;

    float*     Xs  = (float*)smem;
    _Float16*  s16 = (_Float16*)(smem + 65536);
    float*     b1s = (float*)(smem + 98560);

    // ---- prologue: X_b -> LDS (padded), b1 -> LDS ----
    {
        const float* xb = Xg + (size_t)b * (N_ * D_);
        int row = tid >> 4, c0 = (tid & 15) * 16;
        #pragma unroll
        for (int q = 0; q < 4; ++q)
            *(f32x4*)(Xs + row * XPAD + c0 + q * 4) = *(const f32x4*)(xb + row * 256 + c0 + q * 4);
        b1s[tid]       = b1g[tid];
        b1s[tid + 512] = b1g[tid + 512];
    }
    __syncthreads();

    // ---- build A fragments for both j's: P[i][k] = X[i][k] * X[j][k], fp16 ----
    // wave rows: i = rt*16 + l15 (rt=0,1); per-lane k = ks*32 + lg*8 + [0..7]
    f16x8 afrag[2][2][8]; // [jj][rt][ks]
    {
        const float* xja = Xs + (j0 + w) * XPAD;
        const float* xjb = Xs + (j0 + 8 + w) * XPAD;
        #pragma unroll
        for (int ks = 0; ks < 8; ++ks) {
            int k0 = ks * 32 + lg * 8;
            f32x4 jA0 = *(const f32x4*)(xja + k0);
            f32x4 jA1 = *(const f32x4*)(xja + k0 + 4);
            f32x4 jB0 = *(const f32x4*)(xjb + k0);
            f32x4 jB1 = *(const f32x4*)(xjb + k0 + 4);
            #pragma unroll
            for (int rt = 0; rt < 2; ++rt) {
                const float* xi = Xs + (rt * 16 + l15) * XPAD + k0;
                f32x4 x0 = *(const f32x4*)(xi);
                f32x4 x1 = *(const f32x4*)(xi + 4);
                f16x8 a, c;
                a[0] = (_Float16)(x0[0] * jA0[0]); c[0] = (_Float16)(x0[0] * jB0[0]);
                a[1] = (_Float16)(x0[1] * jA0[1]); c[1] = (_Float16)(x0[1] * jB0[1]);
                a[2] = (_Float16)(x0[2] * jA0[2]); c[2] = (_Float16)(x0[2] * jB0[2]);
                a[3] = (_Float16)(x0[3] * jA0[3]); c[3] = (_Float16)(x0[3] * jB0[3]);
                a[4] = (_Float16)(x1[0] * jA1[0]); c[4] = (_Float16)(x1[0] * jB1[0]);
                a[5] = (_Float16)(x1[1] * jA1[1]); c[5] = (_Float16)(x1[1] * jB1[1]);
                a[6] = (_Float16)(x1[2] * jA1[2]); c[6] = (_Float16)(x1[2] * jB1[2]);
                a[7] = (_Float16)(x1[3] * jA1[3]); c[7] = (_Float16)(x1[3] * jB1[3]);
                afrag[0][rt][ks] = a;
                afrag[1][rt][ks] = c;
            }
        }
    }
    __syncthreads(); // X region free -> becomes wbuf0/wbuf1

    // ---- stage W1 chunk c (64 rows x 512 B = 32 KB) into buf (c&1):
    //      linear LDS dest, inverse-XOR-swizzled global source ----
    auto stage = [&](int c) {
        const int bufbase = (c & 1) * 32768;
        #pragma unroll
        for (int p = 0; p < 4; ++p) {
            int hc   = ((p * 8 + w) << 1) + (l >> 5);     // row 0..63 within chunk
            int srco = ((l & 31) ^ (hc & 7)) << 3;        // permuted k-oct
            const _Float16* src = W1T + (size_t)(c * 64 + hc) * 256 + srco;
            void* dst = smem + bufbase + (p * 8 + w) * 1024; // wave-uniform
            gload_lds16(src, dst);
        }
    };

    stage(0);

    for (int c = 0; c < 16; ++c) {
        if (c < 15) {
            stage(c + 1);
            asm volatile("s_waitcnt vmcnt(4)" ::: "memory"); // stage(c) landed
        } else {
            asm volatile("s_waitcnt vmcnt(0)" ::: "memory");
        }
        BARRIER();

        const int bufbase = (c & 1) * 32768;
        f32x4 acc[2][2][4] = {}; // [jj][rt][ct]
        __builtin_amdgcn_s_setprio(1);
        #pragma unroll
        for (int ks = 0; ks < 8; ++ks) {
            #pragma unroll
            for (int ct = 0; ct < 4; ++ct) {
                int hc = ct * 16 + l15;
                int boff = bufbase + hc * 512 + ((ks * 64 + lg * 16) ^ ((hc & 7) << 4));
                f16x8 bfr = *(const f16x8*)(smem + boff);
                acc[0][0][ct] = __builtin_amdgcn_mfma_f32_16x16x32_f16(afrag[0][0][ks], bfr, acc[0][0][ct], 0, 0, 0);
                acc[0][1][ct] = __builtin_amdgcn_mfma_f32_16x16x32_f16(afrag[0][1][ks], bfr, acc[0][1][ct], 0, 0, 0);
                acc[1][0][ct] = __builtin_amdgcn_mfma_f32_16x16x32_f16(afrag[1][0][ks], bfr, acc[1][0][ct], 0, 0, 0);
                acc[1][1][ct] = __builtin_amdgcn_mfma_f32_16x16x32_f16(afrag[1][1][ks], bfr, acc[1][1][ct], 0, 0, 0);
            }
        }
        __builtin_amdgcn_s_setprio(0);

        // epilogue: +b1, ReLU, reduce over 32 i-rows per j, store f16 to s16
        #pragma unroll
        for (int ct = 0; ct < 4; ++ct) {
            int hcol = c * 64 + ct * 16 + l15;
            float bv = b1s[hcol];
            float v0 = 0.f, v1 = 0.f;
            #pragma unroll
            for (int rt = 0; rt < 2; ++rt)
                #pragma unroll
                for (int r = 0; r < 4; ++r) {
                    v0 += fmaxf(acc[0][rt][ct][r] + bv, 0.f);
                    v1 += fmaxf(acc[1][rt][ct][r] + bv, 0.f);
                }
            v0 += __shfl_xor(v0, 16, 64);
            v0 += __shfl_xor(v0, 32, 64);
            v1 += __shfl_xor(v1, 16, 64);
            v1 += __shfl_xor(v1, 32, 64);
            if (lg < 2) { // lanes 0-15 store j-local w; lanes 16-31 store w+8
                int row = w + (lg << 3);
                s16[row * SROW + hcol] = (_Float16)(lg ? v1 : v0);
            }
        }
        BARRIER(); // buf(c&1) fully read before restage at c+2
    }

    __syncthreads(); // s16 complete & visible to all waves

    // ---- fused layer 2: out[j][d] = s16[j][:] @ W2T[d][:] + 32*b2[d] ----
    // A rows = j-local (16), B cols = d (wave w owns d in [w*32, w*32+32)).
    f32x4 acc2[2] = {};
    #pragma unroll
    for (int ks = 0; ks < 32; ++ks) {
        f16x8 af = *(const f16x8*)(s16 + l15 * SROW + ks * 32 + lg * 8);
        #pragma unroll
        for (int t2 = 0; t2 < 2; ++t2) {
            const _Float16* bp = W2T + (size_t)((w * 2 + t2) * 16 + l15) * 1024 + ks * 32 + lg * 8;
            f16x8 bf = *(const f16x8*)bp;
            acc2[t2] = __builtin_amdgcn_mfma_f32_16x16x32_f16(af, bf, acc2[t2], 0, 0, 0);
        }
    }
    #pragma unroll
    for (int t2 = 0; t2 < 2; ++t2) {
        int d = (w * 2 + t2) * 16 + l15;
        float bb = 32.f * b2g[d];
        #pragma unroll
        for (int r = 0; r < 4; ++r) {
            int jloc = lg * 4 + r;
            outg[(size_t)(b * 32 + j0 + jloc) * 256 + d] = acc2[t2][r] + bb;
        }
    }
}

// ---------------------------------------------------------------------------
extern "C" void kernel_launch(void* const* d_in, const int* in_sizes, int n_in,
                              void* d_out, int out_size, void* d_ws, size_t ws_size,
                              hipStream_t stream) {
    const float* X  = (const float*)d_in[0]; // [128,32,256]
    const float* W1 = (const float*)d_in[1]; // [256,1024]
    const float* b1 = (const float*)d_in[2]; // [1024]
    const float* W2 = (const float*)d_in[3]; // [1024,256]
    const float* b2 = (const float*)d_in[4]; // [256]
    float* out = (float*)d_out;              // [128,32,256]

    _Float16* W1T = (_Float16*)d_ws;         // [1024][256]  512 KB
    _Float16* W2T = W1T + 262144;            // [256][1024]  512 KB

    prep2<<<dim3(512), dim3(256), 0, stream>>>(W1, W2, W1T, W2T);
    interaction_main<<<dim3(B_ * (N_ / 16)), dim3(512), 0, stream>>>(X, b1, b2, W1T, W2T, out);
}